// Round 21
// baseline (89.689 us; speedup 1.0000x reference)
//
#include <hip/hip_runtime.h>
#include <math.h>

#define NTOK 16384
#define D_   2048
#define E_   64
#define TPB  16            // tokens per block (16 MFMA rows)
#define NKC  (D_/32)       // 64 k32-steps

typedef _Float16 f16x8 __attribute__((ext_vector_type(8)));
typedef float    f32x4 __attribute__((ext_vector_type(4)));

#define LSCALE      256.0f          // pre-scale x and W before f16 split (denorm guard)
#define LSCALE2_INV (1.0f/65536.0f) // exact pow2 un-scale of acc

// ---- Kernel 1: W (E x D fp32) -> fragment-ordered f16 hi/lo, scaled x256 ----
// Fragment order: element j of lane l for (n-tile nt, k32-step kc) is
//   W[e = nt*16 + (l&15)][k = kc*32 + (l>>4)*4 + (j&3) + (j>=4 ? 16 : 0)]
// Same k-map as the A operand -> any deviation from HW k-order cancels.
__global__ __launch_bounds__(256)
void prep_w(const float* __restrict__ W,
            _Float16* __restrict__ wh, _Float16* __restrict__ wl)
{
    const int idx = blockIdx.x * 256 + threadIdx.x;   // 0..16383
    const int l  = idx & 63;
    const int kc = (idx >> 6) & 63;
    const int nt = idx >> 12;                          // 0..3
    const int e  = nt * 16 + (l & 15);
    const int g  = l >> 4;
    const float* src = W + (size_t)e * D_ + kc * 32 + g * 4;
    const float4 f0 = *reinterpret_cast<const float4*>(src);
    const float4 f1 = *reinterpret_cast<const float4*>(src + 16);
    const float v[8] = {f0.x, f0.y, f0.z, f0.w, f1.x, f1.y, f1.z, f1.w};
    f16x8 h, lo;
#pragma unroll
    for (int j = 0; j < 8; ++j) {
        const float vs = v[j] * LSCALE;
        const _Float16 hj = (_Float16)vs;
        h[j]  = hj;
        lo[j] = (_Float16)(vs - (float)hj);
    }
    *reinterpret_cast<f16x8*>(wh + (size_t)idx * 8) = h;
    *reinterpret_cast<f16x8*>(wl + (size_t)idx * 8) = lo;
}

// compiler-proof 16B load: asm volatile keeps source order (no pass can sink
// it) and the "=v" result stays live until its MFMA use.
#define GLOAD16(dst, ptr) \
    asm volatile("global_load_dwordx4 %0, %1, off" : "=v"(dst) : "v"(ptr))

// ---- Kernel 2: MFMA router -- expert-split waves + asm-load depth-4 ring ----
// 1024 blocks x 256 threads (4 waves). Wave w owns n-tile nt=w (16 experts)
// for the block's 16 tokens, full K. B/wave = 128 KB -> device B = 512 MB
// (proven-minimum profile); x rows shared by the 4 waves via L1.
// ONE change vs round 20: __launch_bounds__(256, 2) -- the (256,4) 128-VGPR
// cap made the allocator SPILL the asm ring to scratch (VGPR=48, +2MB FETCH,
// 89 us). Budget 256 fits ring(64) + working(~40) + addressing(~25).
// Ring: 4 loads/kc (xa, xb, BH, BL), depth 4. Counted vmcnt: steady
// vmcnt(12) = 3 kc in flight; tail 12/8/4/0. sched_barrier(0) after each
// wait (rule 18) and after each prefetch group (pin issue early).
// Per-(token,expert) chain (hh,lh,hl; kc ascending; same cvt, same fragment
// maps) is bitwise-identical to rounds 5-20 (absmax 1.0; do NOT reorder).
__global__ __launch_bounds__(256, 2)
void router_mfma(const float* __restrict__ x,
                 const _Float16* __restrict__ wh,
                 const _Float16* __restrict__ wl,
                 const float* __restrict__ bias,
                 float* __restrict__ out)
{
    __shared__ float smem[TPB * 65 + TPB * 4];   // logits [16][65] + res [16][4]

    const int tid = threadIdx.x;
    const int l   = tid & 63;
    const int w   = __builtin_amdgcn_readfirstlane(tid >> 6);  // nt = 0..3
    const int T0  = blockIdx.x * TPB;
    const int g   = l >> 4;

    const float* xp = x + (size_t)(T0 + (l & 15)) * D_ + g * 4;
    const _Float16* bh_b = wh + (size_t)w * 32768 + (size_t)l * 8;  // + kc*512
    const _Float16* bl_b = wl + (size_t)w * 32768 + (size_t)l * 8;

    f32x4 acc = {0.f, 0.f, 0.f, 0.f};

    f32x4 xa[4], xb[4];           // x ring, slot = kc&3 (static under unroll)
    f16x8 BH[4], BL[4];           // B ring (own nt only)

    // one kc-step compute: cvt (frozen math) + 3 MFMA (frozen chain)
    auto COMPUTE = [&](int j) {   // j is compile-time under #pragma unroll
        f16x8 ah, al_;
        {
            float vs;
            vs = xa[j][0] * LSCALE; ah[0] = (_Float16)vs; al_[0] = (_Float16)(vs - (float)ah[0]);
            vs = xa[j][1] * LSCALE; ah[1] = (_Float16)vs; al_[1] = (_Float16)(vs - (float)ah[1]);
            vs = xa[j][2] * LSCALE; ah[2] = (_Float16)vs; al_[2] = (_Float16)(vs - (float)ah[2]);
            vs = xa[j][3] * LSCALE; ah[3] = (_Float16)vs; al_[3] = (_Float16)(vs - (float)ah[3]);
            vs = xb[j][0] * LSCALE; ah[4] = (_Float16)vs; al_[4] = (_Float16)(vs - (float)ah[4]);
            vs = xb[j][1] * LSCALE; ah[5] = (_Float16)vs; al_[5] = (_Float16)(vs - (float)ah[5]);
            vs = xb[j][2] * LSCALE; ah[6] = (_Float16)vs; al_[6] = (_Float16)(vs - (float)ah[6]);
            vs = xb[j][3] * LSCALE; ah[7] = (_Float16)vs; al_[7] = (_Float16)(vs - (float)ah[7]);
        }
        acc = __builtin_amdgcn_mfma_f32_16x16x32_f16(ah,  BH[j], acc, 0, 0, 0);
        acc = __builtin_amdgcn_mfma_f32_16x16x32_f16(al_, BH[j], acc, 0, 0, 0);
        acc = __builtin_amdgcn_mfma_f32_16x16x32_f16(ah,  BL[j], acc, 0, 0, 0);
    };

    // prologue: issue ring for kc = 0..3 (16 loads, in order)
#pragma unroll
    for (int j = 0; j < 4; ++j) {
        GLOAD16(xa[j], xp + j * 32);
        GLOAD16(xb[j], xp + j * 32 + 16);
        GLOAD16(BH[j], bh_b + j * 512);
        GLOAD16(BL[j], bl_b + j * 512);
    }

    // steady state: s = 0..14 (kc 0..59), prefetch kc+4 after compute
    for (int s = 0; s < 15; ++s) {
        const int K = s << 2;
#pragma unroll
        for (int j = 0; j < 4; ++j) {
            asm volatile("s_waitcnt vmcnt(12)" ::: "memory");  // slot j landed
            __builtin_amdgcn_sched_barrier(0);                 // rule 18 fence
            COMPUTE(j);
            const int kn = K + j + 4;                          // 4..63
            GLOAD16(xa[j], xp + kn * 32);
            GLOAD16(xb[j], xp + kn * 32 + 16);
            GLOAD16(BH[j], bh_b + (size_t)kn * 512);
            GLOAD16(BL[j], bl_b + (size_t)kn * 512);
            __builtin_amdgcn_sched_barrier(0);                 // pin issue early
        }
    }
    // tail: kc 60..63, drain 12/8/4/0
    asm volatile("s_waitcnt vmcnt(12)" ::: "memory");
    __builtin_amdgcn_sched_barrier(0);
    COMPUTE(0);
    asm volatile("s_waitcnt vmcnt(8)" ::: "memory");
    __builtin_amdgcn_sched_barrier(0);
    COMPUTE(1);
    asm volatile("s_waitcnt vmcnt(4)" ::: "memory");
    __builtin_amdgcn_sched_barrier(0);
    COMPUTE(2);
    asm volatile("s_waitcnt vmcnt(0)" ::: "memory");
    __builtin_amdgcn_sched_barrier(0);
    COMPUTE(3);

    // ---- C tile -> LDS logits. C layout: col = lane&15, row = (lane>>4)*4+r ----
    {
        const int col = w * 16 + (l & 15);
#pragma unroll
        for (int r = 0; r < 4; ++r) {
            const int t = g * 4 + r;                  // token 0..15
            smem[t * 65 + col] = acc[r] * LSCALE2_INV;
        }
    }
    __syncthreads();

    // ---- top-2 + 2-way softmax (frozen scan): thread t handles token t ----
    float* res = smem + TPB * 65;
    if (tid < TPB) {
        const float* lg = smem + tid * 65;
        float m1 = -INFINITY, m2 = -INFINITY;
        int i1 = 0, i2 = 0;
        for (int e = 0; e < E_; ++e) {
            const float v = lg[e] + bias[e];
            if (v > m1)      { m2 = m1; i2 = i1; m1 = v; i1 = e; }
            else if (v > m2) { m2 = v;  i2 = e; }
        }
        const float ex  = expf(m2 - m1);
        const float den = 1.f + ex;
        res[tid*4+0] = 1.f / den;
        res[tid*4+1] = ex / den;
        res[tid*4+2] = (float)i1;
        res[tid*4+3] = (float)i2;
    }
    __syncthreads();

    // ---- output: probs (16 tokens x 64 experts = 1024 floats), float4 ----
    float* ob = out + (size_t)T0 * E_;
    {
        const int idx = tid * 4;
        const int t   = idx >> 6;
        const int e0  = idx & 63;
        const float p1 = res[t*4+0];
        const float p2 = res[t*4+1];
        const int   i1 = (int)res[t*4+2];
        const int   i2 = (int)res[t*4+3];
        float4 v;
        v.x = (e0+0 == i1) ? p1 : ((e0+0 == i2) ? p2 : 0.f);
        v.y = (e0+1 == i1) ? p1 : ((e0+1 == i2) ? p2 : 0.f);
        v.z = (e0+2 == i1) ? p1 : ((e0+2 == i2) ? p2 : 0.f);
        v.w = (e0+3 == i1) ? p1 : ((e0+3 == i2) ? p2 : 0.f);
        *reinterpret_cast<float4*>(ob + idx) = v;
    }
    // ids as float values (whole d_out is read as float32)
    if (tid < TPB * 2) {
        out[(size_t)NTOK * E_ + (size_t)T0 * 2 + tid] =
            res[(tid >> 1) * 4 + 2 + (tid & 1)];
    }
}

extern "C" void kernel_launch(void* const* d_in, const int* in_sizes, int n_in,
                              void* d_out, int out_size, void* d_ws, size_t ws_size,
                              hipStream_t stream) {
    const float* x = (const float*)d_in[0];
    const float* W = (const float*)d_in[1];
    const float* b = (const float*)d_in[2];
    float* out     = (float*)d_out;
    _Float16* wh   = (_Float16*)d_ws;                       // 256 KB
    _Float16* wl   = wh + (size_t)4 * NKC * 64 * 8;         // +256 KB

    hipLaunchKernelGGL(prep_w, dim3(64), dim3(256), 0, stream, W, wh, wl);
    hipLaunchKernelGGL(router_mfma, dim3(NTOK / TPB), dim3(256), 0, stream,
                       x, wh, wl, b, out);
}

// Round 22
// 49.178 us; speedup vs baseline: 1.8238x; 1.8238x over previous
//
#include <hip/hip_runtime.h>
#include <math.h>

#define NTOK 16384
#define D_   2048
#define E_   64
#define TPB  16            // tokens per block (= per wave)
#define NKC  (D_/32)       // 64 k32-steps

typedef _Float16 f16x8 __attribute__((ext_vector_type(8)));
typedef float    f32x4 __attribute__((ext_vector_type(4)));

#define LSCALE      256.0f          // pre-scale x and W before f16 split (denorm guard)
#define LSCALE2_INV (1.0f/65536.0f) // exact pow2 un-scale of acc

// ---- Kernel 1: W (E x D fp32) -> fragment-ordered f16 hi/lo, scaled x256 ----
// Fragment order: element j of lane l for (n-tile nt, k32-step kc) is
//   W[e = nt*16 + (l&15)][k = kc*32 + (l>>4)*4 + (j&3) + (j>=4 ? 16 : 0)]
// Same k-map as the A operand -> any deviation from HW k-order cancels.
__global__ __launch_bounds__(256)
void prep_w(const float* __restrict__ W,
            _Float16* __restrict__ wh, _Float16* __restrict__ wl)
{
    const int idx = blockIdx.x * 256 + threadIdx.x;   // 0..16383
    const int l  = idx & 63;
    const int kc = (idx >> 6) & 63;
    const int nt = idx >> 12;                          // 0..3
    const int e  = nt * 16 + (l & 15);
    const int g  = l >> 4;
    const float* src = W + (size_t)e * D_ + kc * 32 + g * 4;
    const float4 f0 = *reinterpret_cast<const float4*>(src);
    const float4 f1 = *reinterpret_cast<const float4*>(src + 16);
    const float v[8] = {f0.x, f0.y, f0.z, f0.w, f1.x, f1.y, f1.z, f1.w};
    f16x8 h, lo;
#pragma unroll
    for (int j = 0; j < 8; ++j) {
        const float vs = v[j] * LSCALE;
        const _Float16 hj = (_Float16)vs;
        h[j]  = hj;
        lo[j] = (_Float16)(vs - (float)hj);
    }
    *reinterpret_cast<f16x8*>(wh + (size_t)idx * 8) = h;
    *reinterpret_cast<f16x8*>(wl + (size_t)idx * 8) = lo;
}

// ---- Kernel 2: MFMA router -- r15 structure + depth-8 x ring (r19, BEST) ----
// 1024 blocks x 64 threads (1 wave = 16 tokens x all 64 experts, 4 acc tiles).
// Session-final kernel: 49.3 us (r19). The depth-8 x ring / depth-4 B ring
// with sched_barrier(0) fences is the deepest pipeline this toolchain
// sustains (VGPR 136; r12-r21 showed every deeper ring -- intrinsic, asm,
// LDS-private, or budget-raised -- gets collapsed or spilled by the
// allocator). Remaining time is exposed L3/L2 latency.
// Per-(token,expert) chain (hh,lh,hl; nt 0..3; kc ascending; same cvt, same
// fragment maps) is bitwise-identical to rounds 5-21 (absmax 1.0; do NOT
// reorder).
__global__ __launch_bounds__(64, 1)
void router_mfma(const float* __restrict__ x,
                 const _Float16* __restrict__ wh,
                 const _Float16* __restrict__ wl,
                 const float* __restrict__ bias,
                 float* __restrict__ out)
{
    __shared__ float smem[TPB * 65 + TPB * 4];   // logits [16][65] + res [16][4]

    const int l  = threadIdx.x;                  // 0..63, one wave
    const int T0 = blockIdx.x * TPB;
    const int g  = l >> 4;

    const float* xp = x + (size_t)(T0 + (l & 15)) * D_ + g * 4;
    const _Float16* bh_b = wh + (size_t)l * 8;   // + nt*32768 + kc*512
    const _Float16* bl_b = wl + (size_t)l * 8;

    f32x4 acc0 = {0.f,0.f,0.f,0.f}, acc1 = {0.f,0.f,0.f,0.f};
    f32x4 acc2 = {0.f,0.f,0.f,0.f}, acc3 = {0.f,0.f,0.f,0.f};

    float4 xa[8], xb[8];          // x ring, slot = kc&7 (static via pairing)
    f16x8  BH[4][4], BL[4][4];    // B ring, slot = kc&3, [slot][nt]

    // one kc-step: cvt (frozen) + 12 MFMA (frozen chain) + optional prefetch
    auto STEP = [&](float4& XA, float4& XB, f16x8 (&BHj)[4], f16x8 (&BLj)[4],
                    int kc, bool pfx, bool pfb) {
        f16x8 ah, al_;
        {
            float vs;
            vs = XA.x * LSCALE; ah[0] = (_Float16)vs; al_[0] = (_Float16)(vs - (float)ah[0]);
            vs = XA.y * LSCALE; ah[1] = (_Float16)vs; al_[1] = (_Float16)(vs - (float)ah[1]);
            vs = XA.z * LSCALE; ah[2] = (_Float16)vs; al_[2] = (_Float16)(vs - (float)ah[2]);
            vs = XA.w * LSCALE; ah[3] = (_Float16)vs; al_[3] = (_Float16)(vs - (float)ah[3]);
            vs = XB.x * LSCALE; ah[4] = (_Float16)vs; al_[4] = (_Float16)(vs - (float)ah[4]);
            vs = XB.y * LSCALE; ah[5] = (_Float16)vs; al_[5] = (_Float16)(vs - (float)ah[5]);
            vs = XB.z * LSCALE; ah[6] = (_Float16)vs; al_[6] = (_Float16)(vs - (float)ah[6]);
            vs = XB.w * LSCALE; ah[7] = (_Float16)vs; al_[7] = (_Float16)(vs - (float)ah[7]);
        }
        acc0 = __builtin_amdgcn_mfma_f32_16x16x32_f16(ah,  BHj[0], acc0, 0, 0, 0);
        acc0 = __builtin_amdgcn_mfma_f32_16x16x32_f16(al_, BHj[0], acc0, 0, 0, 0);
        acc0 = __builtin_amdgcn_mfma_f32_16x16x32_f16(ah,  BLj[0], acc0, 0, 0, 0);
        acc1 = __builtin_amdgcn_mfma_f32_16x16x32_f16(ah,  BHj[1], acc1, 0, 0, 0);
        acc1 = __builtin_amdgcn_mfma_f32_16x16x32_f16(al_, BHj[1], acc1, 0, 0, 0);
        acc1 = __builtin_amdgcn_mfma_f32_16x16x32_f16(ah,  BLj[1], acc1, 0, 0, 0);
        acc2 = __builtin_amdgcn_mfma_f32_16x16x32_f16(ah,  BHj[2], acc2, 0, 0, 0);
        acc2 = __builtin_amdgcn_mfma_f32_16x16x32_f16(al_, BHj[2], acc2, 0, 0, 0);
        acc2 = __builtin_amdgcn_mfma_f32_16x16x32_f16(ah,  BLj[2], acc2, 0, 0, 0);
        acc3 = __builtin_amdgcn_mfma_f32_16x16x32_f16(ah,  BHj[3], acc3, 0, 0, 0);
        acc3 = __builtin_amdgcn_mfma_f32_16x16x32_f16(al_, BHj[3], acc3, 0, 0, 0);
        acc3 = __builtin_amdgcn_mfma_f32_16x16x32_f16(ah,  BLj[3], acc3, 0, 0, 0);
        if (pfx) {   // refill this x slot with kc+8
            XA = *reinterpret_cast<const float4*>(xp + (kc + 8) * 32);
            XB = *reinterpret_cast<const float4*>(xp + (kc + 8) * 32 + 16);
        }
        if (pfb) {   // refill this B slot with kc+4
#pragma unroll
            for (int nt = 0; nt < 4; ++nt) {
                BHj[nt] = *reinterpret_cast<const f16x8*>(bh_b + nt * 32768 + (size_t)(kc + 4) * 512);
                BLj[nt] = *reinterpret_cast<const f16x8*>(bl_b + nt * 32768 + (size_t)(kc + 4) * 512);
            }
        }
        __builtin_amdgcn_sched_barrier(0);   // PIN: prefetches may not sink
    };

    // prologue: x kc 0..7 (8 slots), B kc 0..3 (4 slots)
#pragma unroll
    for (int j = 0; j < 4; ++j) {
        xa[j]     = *reinterpret_cast<const float4*>(xp + j * 32);
        xb[j]     = *reinterpret_cast<const float4*>(xp + j * 32 + 16);
        xa[4 + j] = *reinterpret_cast<const float4*>(xp + (4 + j) * 32);
        xb[4 + j] = *reinterpret_cast<const float4*>(xp + (4 + j) * 32 + 16);
#pragma unroll
        for (int nt = 0; nt < 4; ++nt) {
            BH[j][nt] = *reinterpret_cast<const f16x8*>(bh_b + nt * 32768 + j * 512);
            BL[j][nt] = *reinterpret_cast<const f16x8*>(bl_b + nt * 32768 + j * 512);
        }
    }

    // steady state: superstep pairs m = 0..6 (s = 0..13), full prefetch.
    // max x prefetch kc+8 = (48+4+3)+8 = 63; max B prefetch at s=14: 59+4 = 63.
    for (int m = 0; m < 7; ++m) {
        const int K = m << 3;
#pragma unroll
        for (int j = 0; j < 4; ++j)      // even superstep: x slots 0-3
            STEP(xa[j], xb[j], BH[j], BL[j], K + j, true, true);
#pragma unroll
        for (int j = 0; j < 4; ++j)      // odd superstep: x slots 4-7
            STEP(xa[4 + j], xb[4 + j], BH[j], BL[j], K + 4 + j, true, true);
    }
    // s = 14 (kc 56..59): B prefetch only
#pragma unroll
    for (int j = 0; j < 4; ++j)
        STEP(xa[j], xb[j], BH[j], BL[j], 56 + j, false, true);
    // s = 15 (kc 60..63): peeled, no prefetch
#pragma unroll
    for (int j = 0; j < 4; ++j)
        STEP(xa[4 + j], xb[4 + j], BH[j], BL[j], 60 + j, false, false);

    // ---- C tiles -> LDS logits. C layout: col = lane&15, row = (lane>>4)*4+r ----
    {
        const int col = l & 15;
#pragma unroll
        for (int r = 0; r < 4; ++r) {
            const int t = g * 4 + r;
            smem[t * 65 + 0  + col] = acc0[r] * LSCALE2_INV;
            smem[t * 65 + 16 + col] = acc1[r] * LSCALE2_INV;
            smem[t * 65 + 32 + col] = acc2[r] * LSCALE2_INV;
            smem[t * 65 + 48 + col] = acc3[r] * LSCALE2_INV;
        }
    }
    __syncthreads();   // single wave: LDS drain

    // ---- top-2 + 2-way softmax (frozen scan): lane t handles token t ----
    float* res = smem + TPB * 65;
    if (l < TPB) {
        const float* lg = smem + l * 65;
        float m1 = -INFINITY, m2 = -INFINITY;
        int i1 = 0, i2 = 0;
        for (int e = 0; e < E_; ++e) {
            const float v = lg[e] + bias[e];
            if (v > m1)      { m2 = m1; i2 = i1; m1 = v; i1 = e; }
            else if (v > m2) { m2 = v;  i2 = e; }
        }
        const float ex  = expf(m2 - m1);
        const float den = 1.f + ex;
        res[l*4+0] = 1.f / den;
        res[l*4+1] = ex / den;
        res[l*4+2] = (float)i1;
        res[l*4+3] = (float)i2;
    }
    __syncthreads();

    // ---- output: probs (16 tokens x 64 experts = 1024 floats), float4 ----
    float* ob = out + (size_t)T0 * E_;
#pragma unroll
    for (int i = 0; i < 4; ++i) {
        const int idx = i * 256 + l * 4;
        const int t   = idx >> 6;
        const int e0  = idx & 63;
        const float p1 = res[t*4+0];
        const float p2 = res[t*4+1];
        const int   i1 = (int)res[t*4+2];
        const int   i2 = (int)res[t*4+3];
        float4 v;
        v.x = (e0+0 == i1) ? p1 : ((e0+0 == i2) ? p2 : 0.f);
        v.y = (e0+1 == i1) ? p1 : ((e0+1 == i2) ? p2 : 0.f);
        v.z = (e0+2 == i1) ? p1 : ((e0+2 == i2) ? p2 : 0.f);
        v.w = (e0+3 == i1) ? p1 : ((e0+3 == i2) ? p2 : 0.f);
        *reinterpret_cast<float4*>(ob + idx) = v;
    }
    // ids as float values (whole d_out is read as float32)
    if (l < TPB * 2) {
        out[(size_t)NTOK * E_ + (size_t)T0 * 2 + l] =
            res[(l >> 1) * 4 + 2 + (l & 1)];
    }
}

extern "C" void kernel_launch(void* const* d_in, const int* in_sizes, int n_in,
                              void* d_out, int out_size, void* d_ws, size_t ws_size,
                              hipStream_t stream) {
    const float* x = (const float*)d_in[0];
    const float* W = (const float*)d_in[1];
    const float* b = (const float*)d_in[2];
    float* out     = (float*)d_out;
    _Float16* wh   = (_Float16*)d_ws;                       // 256 KB
    _Float16* wl   = wh + (size_t)4 * NKC * 64 * 8;         // +256 KB

    hipLaunchKernelGGL(prep_w, dim3(64), dim3(256), 0, stream, W, wh, wl);
    hipLaunchKernelGGL(router_mfma, dim3(NTOK / TPB), dim3(64), 0, stream,
                       x, wh, wl, b, out);
}